// Round 6
// baseline (215.384 us; speedup 1.0000x reference)
//
#include <hip/hip_runtime.h>
#include <math.h>

// Problem constants
#define VDIM   128
#define KCODES 512
#define NROWS  (32 * 4096)      // 131072
#define TILE_ROWS 64            // rows per block (4 waves x 16 rows)
#define NBLOCKS (NROWS / TILE_ROWS)     // 2048
#define STAGE_CODES 64          // codes staged in LDS per stage (16 KB)
#define STAGE_GRAN (STAGE_CODES * 16)   // 1024 16B granules per stage
#define TN 0.67882250993908565f // 0.06 * sqrt(128)

typedef __attribute__((ext_vector_type(8))) short bf16x8;  // MFMA A/B frag (4 VGPR)
typedef __attribute__((ext_vector_type(4))) float f32x4;   // MFMA C/D frag

__device__ __forceinline__ unsigned short f2bf(float f) {
    unsigned u = __float_as_uint(f);
    unsigned r = u + 0x7FFFu + ((u >> 16) & 1u);   // round-to-nearest-even
    return (unsigned short)(r >> 16);
}

__device__ __forceinline__ float bf2f(unsigned short h) {
    return __uint_as_float(((unsigned)h) << 16);
}

__device__ __forceinline__ bf16x8 pack8(float4 a, float4 b) {
    bf16x8 v;
    v[0] = (short)f2bf(a.x); v[1] = (short)f2bf(a.y);
    v[2] = (short)f2bf(a.z); v[3] = (short)f2bf(a.w);
    v[4] = (short)f2bf(b.x); v[5] = (short)f2bf(b.y);
    v[6] = (short)f2bf(b.z); v[7] = (short)f2bf(b.w);
    return v;
}

// Normalize codes -> bf16 table (row-major), used for both MFMA B and gather
__global__ void prep_emb(const float* __restrict__ emb0,
                         unsigned short* __restrict__ ebf) {
    int k = blockIdx.x;       // KCODES blocks
    int l = threadIdx.x;      // 64 threads = 1 wave
    const float* row = emb0 + (size_t)k * VDIM;
    float a = row[l];
    float b = row[l + 64];
    float ss = a * a + b * b;
    #pragma unroll
    for (int off = 32; off; off >>= 1) ss += __shfl_xor(ss, off);
    float nrm = sqrtf(ss);
    ebf[(size_t)k * VDIM + l]      = f2bf((TN * a) / nrm);
    ebf[(size_t)k * VDIM + l + 64] = f2bf((TN * b) / nrm);
}

// Main: 4 waves x 16 rows. A frags in VGPRs; B staged through LDS in 8 x 16KB
// stages, lane-linear fragment order (stride-1 ds_write/ds_read, no conflicts).
// argmin(dist) == argmax(dot(x0,e)) since ||x|| = ||e|| = tn exactly.
// Entropy fused via completion-counter last-block pattern.
__global__ __launch_bounds__(256, 8) void vq_main(
        const float* __restrict__ x0,
        const unsigned short* __restrict__ ebf,
        unsigned* __restrict__ hist,
        unsigned* __restrict__ counter,
        float* __restrict__ out0,
        float* __restrict__ out1,
        float* __restrict__ out2,
        float* __restrict__ oent) {
    __shared__ uint4 sB[STAGE_GRAN];        // 16 KB staged B fragments
    __shared__ int   sbesti[TILE_ROWS];
    __shared__ float sdot[TILE_ROWS];
    __shared__ float sn0[TILE_ROWS];
    __shared__ float sred[8];
    __shared__ int   slast;

    int t = threadIdx.x;
    int w = t >> 6;           // wave 0..3
    int l = t & 63;
    int n15 = l & 15;         // MFMA m (A rows), n (B cols), col (C)
    int q = l >> 4;           // quad: input k = q*8 + j; C row = q*4 + r

    // ---- Load A: 16 rows/wave, K=128 as 4 k-chunks; fp32 -> bf16 frags
    int rowbase = blockIdx.x * TILE_ROWS + (w << 4);
    bf16x8 afr[4];
    float nsq;
    {
        const float* xrow = x0 + (size_t)(rowbase + n15) * VDIM + (q << 3);
        float p0 = 0.f, p1 = 0.f;
        #pragma unroll
        for (int kc = 0; kc < 4; ++kc) {
            const float4* xp = (const float4*)(xrow + (kc << 5));
            float4 a = xp[0], b = xp[1];
            p0 = fmaf(a.x, a.x, p0); p1 = fmaf(a.y, a.y, p1);
            p0 = fmaf(a.z, a.z, p0); p1 = fmaf(a.w, a.w, p1);
            p0 = fmaf(b.x, b.x, p0); p1 = fmaf(b.y, b.y, p1);
            p0 = fmaf(b.z, b.z, p0); p1 = fmaf(b.w, b.w, p1);
            afr[kc] = pack8(a, b);
        }
        nsq = p0 + p1;
        nsq += __shfl_xor(nsq, 16, 64);   // reduce ||x0||^2 across quads
        nsq += __shfl_xor(nsq, 32, 64);
    }

    float best[4];
    int   bidx[4];
    #pragma unroll
    for (int r = 0; r < 4; ++r) { best[r] = -3.4e38f; bidx[r] = 0; }

    const f32x4 zero4 = {0.f, 0.f, 0.f, 0.f};
    const uint4* ebg = (const uint4*)ebf;       // 16B-granule view of code table

    // ---- 8 stages of 64 codes each
    for (int st = 0; st < 8; ++st) {
        if (st) __syncthreads();                // previous stage fully consumed

        // Stage: LDS granule lid = r*256 + t (stride-1 ds_write_b128).
        // lid -> (chunk c=r, kc=t>>6, q=(t>>4)&3, n=t&15); per-wave global
        // reads are 16 x 64B contiguous segments.
        #pragma unroll
        for (int r = 0; r < 4; ++r) {
            int code = st * STAGE_CODES + (r << 4) + (t & 15);
            int gran = ((t >> 6) << 2) + ((t >> 4) & 3);
            sB[(r << 8) + t] = ebg[(size_t)code * 16 + gran];
        }
        __syncthreads();

        // 4 chunks of 16 codes from LDS (lane-linear frags: stride-1 reads)
        #pragma unroll
        for (int c = 0; c < 4; ++c) {
            const bf16x8* bls = ((const bf16x8*)sB) + (c << 8) + l;
            bf16x8 b0 = bls[0], b1 = bls[64], b2 = bls[128], b3 = bls[192];
            int nbase = st * STAGE_CODES + (c << 4) + n15;
            f32x4 acc = __builtin_amdgcn_mfma_f32_16x16x32_bf16(afr[0], b0, zero4, 0, 0, 0);
            acc = __builtin_amdgcn_mfma_f32_16x16x32_bf16(afr[1], b1, acc, 0, 0, 0);
            acc = __builtin_amdgcn_mfma_f32_16x16x32_bf16(afr[2], b2, acc, 0, 0, 0);
            acc = __builtin_amdgcn_mfma_f32_16x16x32_bf16(afr[3], b3, acc, 0, 0, 0);
            #pragma unroll
            for (int r = 0; r < 4; ++r) {
                float d = acc[r];
                if (d > best[r]) { best[r] = d; bidx[r] = nbase; }
            }
        }
    }

    // ---- Reduce argmax across the 16 lanes (C cols) holding the same row
    #pragma unroll
    for (int m = 1; m <= 8; m <<= 1) {
        #pragma unroll
        for (int r = 0; r < 4; ++r) {
            float ov = __shfl_xor(best[r], m, 64);
            int   oi = __shfl_xor(bidx[r], m, 64);
            if (ov > best[r] || (ov == best[r] && oi < bidx[r])) {
                best[r] = ov; bidx[r] = oi;
            }
        }
    }

    // ---- Stage per-row results to LDS for the coalesced epilogue
    if (n15 == 0) {
        #pragma unroll
        for (int r = 0; r < 4; ++r) {
            int lr = (w << 4) + (q << 2) + r;     // C row = q*4+r
            sbesti[lr] = bidx[r];
            sdot[lr]   = best[r];
        }
    }
    if (q == 0) sn0[(w << 4) + n15] = nsq;
    __syncthreads();

    // ---- Epilogue A: coalesced out0 (32 lanes cover one row; bf16 gather)
    size_t blockrow = (size_t)blockIdx.x * TILE_ROWS;
    #pragma unroll
    for (int pass = 0; pass < 8; ++pass) {
        int lr = (pass << 3) + (t >> 5);   // 8 rows per pass
        int v4 = t & 31;                   // float4 slot within the row
        int bi = sbesti[lr];
        const unsigned short* ep = ebf + (size_t)bi * VDIM + (v4 << 2);
        float4 e = make_float4(bf2f(ep[0]), bf2f(ep[1]), bf2f(ep[2]), bf2f(ep[3]));
        ((float4*)(out0 + (blockrow + lr) * (size_t)VDIM))[v4] = e;
    }

    // ---- Epilogue B: per-row scalars (threads 0..63)
    if (t < TILE_ROWS) {
        size_t row = blockrow + t;
        int bi = sbesti[t];
        float dotv = sdot[t];
        float nn = sn0[t];
        float sc = TN / sqrtf(nn);                      // x = sc * x0
        float o1 = 2.f * TN * TN - 2.f * sc * dotv;     // ||x||^2=||e||^2=tn^2
        out1[row] = o1;
        float sm = sc - 1.f;
        out2[row] = o1 + sm * sm * nn;                  // + sum (x-x0)^2
        atomicAdd(&hist[bi], 1u);
    }

    // ---- Fused entropy: last block to finish computes it
    __syncthreads();
    if (t == 0) {
        __threadfence();                                // hist atomics visible
        unsigned prev = atomicAdd(counter, 1u);
        slast = (prev == (unsigned)(NBLOCKS - 1));
    }
    __syncthreads();
    if (slast) {
        float term = 0.f;
        #pragma unroll
        for (int i = 0; i < 2; ++i) {
            unsigned hv = __hip_atomic_load(&hist[t + (i << 8)],
                                            __ATOMIC_RELAXED,
                                            __HIP_MEMORY_SCOPE_AGENT);
            float h = (float)hv;
            if (h > 0.f) {
                float p = h / (float)NROWS;
                term += p * logf(p);
            }
        }
        #pragma unroll
        for (int off = 32; off; off >>= 1) term += __shfl_xor(term, off);
        if (l == 0) sred[w] = term;
        __syncthreads();
        if (t == 0) {
            float ssum = sred[0] + sred[1] + sred[2] + sred[3];
            oent[0] = -ssum;
        }
    }
}

extern "C" void kernel_launch(void* const* d_in, const int* in_sizes, int n_in,
                              void* d_out, int out_size, void* d_ws, size_t ws_size,
                              hipStream_t stream) {
    const float* x0   = (const float*)d_in[0];
    const float* emb0 = (const float*)d_in[1];

    unsigned short* ebf = (unsigned short*)d_ws;             // 512*128 bf16 = 128 KB
    unsigned* hist = (unsigned*)(ebf + (size_t)KCODES * VDIM);  // 512 u32
    unsigned* counter = hist + KCODES;                       // 1 u32

    float* out  = (float*)d_out;
    float* out0 = out;
    float* out1 = out0 + (size_t)NROWS * VDIM;
    float* out2 = out1 + NROWS;
    float* oent = out2 + NROWS;

    hipMemsetAsync(hist, 0, (KCODES + 1) * sizeof(unsigned), stream);
    prep_emb<<<KCODES, 64, 0, stream>>>(emb0, ebf);
    vq_main<<<NBLOCKS, 256, 0, stream>>>(x0, ebf, hist, counter,
                                         out0, out1, out2, oent);
}